// Round 8
// baseline (195.020 us; speedup 1.0000x reference)
//
#include <hip/hip_runtime.h>

#define CDIM 512
#define OKD  256
#define NDIM 4096

// ws float offsets
#define OFF_XMH 0          // fp32 B*C*64 = 131072
#define OFF_X1  131072     // fp32 B*C*16 = 32768
#define OFF_M1A 163840     // bf16 fragment-layout M1: 4b*8192 ushort = 16384 float slots
#define OFF_CB1 180224     // 64
#define OFF_VMB 180288     // bf16 vm [b][c][w]: 131072 ushort = 65536 float slots

typedef float f32x4  __attribute__((ext_vector_type(4)));
typedef short shortx4 __attribute__((ext_vector_type(4)));
typedef short shortx8 __attribute__((ext_vector_type(8)));

static __device__ __forceinline__ unsigned short f2bf(float f) {
  unsigned u = __float_as_uint(f);
  u = (u + 0x7FFFu + ((u >> 16) & 1u)) >> 16;
  return (unsigned short)u;
}
static __device__ __forceinline__ unsigned pk2(float lo, float hi) {
  return (unsigned)f2bf(lo) | ((unsigned)f2bf(hi) << 16);
}

// ---------------------------------------------------------------------------
// K1: x -> xmh[b,c,64] (h-mean, fp32) and x1pe[b,c,16] (h-mean + 4w-mean + pe)
__global__ __launch_bounds__(256) void k_reduce(const float* __restrict__ x,
                                                const float* __restrict__ pe,
                                                const int* __restrict__ pos,
                                                float* __restrict__ xmh,
                                                float* __restrict__ x1pe) {
  int t = threadIdx.x;
  int bc = blockIdx.x * 4 + (t >> 6);   // B*C = 2048, grid 512
  int w4 = t & 15;
  int hoff = (t >> 4) & 3;
  const float4* xp = (const float4*)(x) + (size_t)bc * (64 * 16);
  float4 acc = make_float4(0.f, 0.f, 0.f, 0.f);
#pragma unroll
  for (int k = 0; k < 16; ++k) {
    float4 v = xp[(hoff + 4 * k) * 16 + w4];
    acc.x += v.x; acc.y += v.y; acc.z += v.z; acc.w += v.w;
  }
  acc.x += __shfl_xor(acc.x, 16); acc.y += __shfl_xor(acc.y, 16);
  acc.z += __shfl_xor(acc.z, 16); acc.w += __shfl_xor(acc.w, 16);
  acc.x += __shfl_xor(acc.x, 32); acc.y += __shfl_xor(acc.y, 32);
  acc.z += __shfl_xor(acc.z, 32); acc.w += __shfl_xor(acc.w, 32);
  if (hoff == 0) {
    const float inv = 1.f / 64.f;
    float4 o = make_float4(acc.x * inv, acc.y * inv, acc.z * inv, acc.w * inv);
    ((float4*)xmh)[bc * 16 + w4] = o;
    int b = bc >> 9;
    int c = bc & 511;
    int ps = pos[b * 4096 + 4 * w4] >> 3;
    float x1 = (o.x + o.y + o.z + o.w) * 0.25f + pe[ps * CDIM + c];
    x1pe[bc * 16 + w4] = x1;
  }
}

// ---------------------------------------------------------------------------
// K2 "mid" (256 thr):
//  blocks 0..31: vm MFMA: vmb[b,c,w] = bf16(Wv@xmh + bv)  (4 waves, wid 0..127)
//  blocks 32..35: per-b fused K1 -> M1 -> cb1:
//     stage 1 (MFMA): K1[b] = Wk@x1pe[b] + bk  -> LDS fp32 [256][17]
//     stage 2 (MFMA): m1A = bf16frag(Wq^T @ K1) ; cb1[b,i] = bq . K1 (shfl dot)
__global__ __launch_bounds__(256) void k_mid(const float* __restrict__ Wv,
                                             const float* __restrict__ bv,
                                             const float* __restrict__ Wk,
                                             const float* __restrict__ bk,
                                             const float* __restrict__ Wq,
                                             const float* __restrict__ bq,
                                             const float* __restrict__ xmh,
                                             const float* __restrict__ x1pe,
                                             unsigned short* __restrict__ vmb,
                                             unsigned short* __restrict__ m1A,
                                             float* __restrict__ cb1) {
  __shared__ float k1s[256][17];   // 17408 B
  int t = threadIdx.x;
  int blk = blockIdx.x;
  int lane = t & 63, nrel = lane & 15, kg = lane >> 4;
  if (blk < 32) {
    int wid = blk * 4 + (t >> 6);   // 0..127
    int b = wid >> 5, rem = wid & 31, cgrp = rem >> 2, wt = rem & 3;
    f32x4 acc[4] = {{0,0,0,0},{0,0,0,0},{0,0,0,0},{0,0,0,0}};
    for (int kt = 0; kt < 16; ++kt) {
      const float* xp = xmh + (size_t)(b * 512 + kt * 32 + kg * 4) * 64 + wt * 16 + nrel;
      float v0 = xp[0], v1 = xp[64], v2 = xp[128], v3 = xp[192];
      float v4 = xp[1024], v5 = xp[1088], v6 = xp[1152], v7 = xp[1216];
      shortx8 bf;
      unsigned* bu = (unsigned*)&bf;
      bu[0] = pk2(v0, v1); bu[1] = pk2(v2, v3);
      bu[2] = pk2(v4, v5); bu[3] = pk2(v6, v7);
#pragma unroll
      for (int m = 0; m < 4; ++m) {
        int c = (cgrp * 4 + m) * 16 + nrel;
        const float* wp = Wv + (size_t)c * 512 + kt * 32 + kg * 4;
        float4 a0 = *(const float4*)wp;
        float4 a1 = *(const float4*)(wp + 16);
        shortx8 af;
        unsigned* au = (unsigned*)&af;
        au[0] = pk2(a0.x, a0.y); au[1] = pk2(a0.z, a0.w);
        au[2] = pk2(a1.x, a1.y); au[3] = pk2(a1.z, a1.w);
        acc[m] = __builtin_amdgcn_mfma_f32_16x16x32_bf16(af, bf, acc[m], 0, 0, 0);
      }
    }
#pragma unroll
    for (int m = 0; m < 4; ++m)
#pragma unroll
      for (int r = 0; r < 4; ++r) {
        int c = (cgrp * 4 + m) * 16 + kg * 4 + r;
        vmb[(size_t)(b * 512 + c) * 64 + wt * 16 + nrel] = f2bf(acc[m][r] + bv[c]);
      }
  } else {
    int b = blk - 32;
    int wvi = t >> 6;               // wave 0..3
    // ---- stage 1: K1[b] = Wk @ x1pe[b] + bk -> LDS ----
#pragma unroll
    for (int oti = 0; oti < 4; ++oti) {
      int ot = wvi * 4 + oti;       // o-tile 0..15
      f32x4 acc = {0.f, 0.f, 0.f, 0.f};
#pragma unroll
      for (int kt = 0; kt < 16; ++kt) {
        int o = ot * 16 + nrel;
        const float* wp = Wk + (size_t)o * 512 + kt * 32 + kg * 4;
        float4 a0 = *(const float4*)wp;
        float4 a1 = *(const float4*)(wp + 16);
        shortx8 af;
        unsigned* au = (unsigned*)&af;
        au[0] = pk2(a0.x, a0.y); au[1] = pk2(a0.z, a0.w);
        au[2] = pk2(a1.x, a1.y); au[3] = pk2(a1.z, a1.w);
        const float* xp = x1pe + (size_t)(b * 512 + kt * 32 + kg * 4) * 16 + nrel;
        float b0 = xp[0],   b1 = xp[16],  b2 = xp[32],  b3 = xp[48];
        float b4 = xp[256], b5 = xp[272], b6 = xp[288], b7 = xp[304];
        shortx8 bf;
        unsigned* bu = (unsigned*)&bf;
        bu[0] = pk2(b0, b1); bu[1] = pk2(b2, b3);
        bu[2] = pk2(b4, b5); bu[3] = pk2(b6, b7);
        acc = __builtin_amdgcn_mfma_f32_16x16x32_bf16(af, bf, acc, 0, 0, 0);
      }
#pragma unroll
      for (int r = 0; r < 4; ++r) {
        int o = ot * 16 + kg * 4 + r;
        k1s[o][nrel] = acc[r] + bk[o];
      }
    }
    __syncthreads();
    // ---- stage 2: m1A = bf16frag(Wq^T @ K1) ----
#pragma unroll
    for (int cti = 0; cti < 8; ++cti) {
      int ct = wvi * 8 + cti;       // c-tile 0..31
      f32x4 acc = {0.f, 0.f, 0.f, 0.f};
#pragma unroll
      for (int kt = 0; kt < 8; ++kt) {
        const float* wqp = Wq + (size_t)(kt * 32 + kg * 4) * CDIM + ct * 16 + nrel;
        float a0 = wqp[0],         a1 = wqp[CDIM],      a2 = wqp[2 * CDIM],  a3 = wqp[3 * CDIM];
        float a4 = wqp[16 * CDIM], a5 = wqp[17 * CDIM], a6 = wqp[18 * CDIM], a7 = wqp[19 * CDIM];
        shortx8 af;
        unsigned* au = (unsigned*)&af;
        au[0] = pk2(a0, a1); au[1] = pk2(a2, a3);
        au[2] = pk2(a4, a5); au[3] = pk2(a6, a7);
        const float* kp = &k1s[kt * 32 + kg * 4][0] + nrel;
        float b0 = kp[0],      b1 = kp[17],     b2 = kp[34],     b3 = kp[51];
        float b4 = kp[16*17],  b5 = kp[17*17],  b6 = kp[18*17],  b7 = kp[19*17];
        shortx8 bf;
        unsigned* bu = (unsigned*)&bf;
        bu[0] = pk2(b0, b1); bu[1] = pk2(b2, b3);
        bu[2] = pk2(b4, b5); bu[3] = pk2(b6, b7);
        acc = __builtin_amdgcn_mfma_f32_16x16x32_bf16(af, bf, acc, 0, 0, 0);
      }
#pragma unroll
      for (int r = 0; r < 4; ++r) {
        int c = ct * 16 + kg * 4 + r;
        int ktm = c >> 5, klm = c & 31;
        int kgm = (klm < 16) ? (klm >> 2) : ((klm - 16) >> 2);
        int jm = (klm & 3) + ((klm < 16) ? 0 : 4);
        m1A[(size_t)b * 8192 + ((size_t)(ktm * 16 + nrel) * 4 + kgm) * 8 + jm] = f2bf(acc[r]);
      }
    }
    // ---- cb1[b,i] = bq . K1[b,:,i] (wave 0, shfl-reduced) ----
    if (t < 64) {
      int i = t & 15, og = t >> 4;    // og 0..3 -> o in [og*64, og*64+64)
      float s = 0.f;
#pragma unroll 8
      for (int m = 0; m < 64; ++m) s += bq[og * 64 + m] * k1s[og * 64 + m][i];
      s += __shfl_xor(s, 16);
      s += __shfl_xor(s, 32);
      if (og == 0) cb1[b * 16 + i] = s;
    }
  }
}

// ---------------------------------------------------------------------------
// K3: fused attention per (b, 32-n tile), 512 thr, 2 barriers. (R5 verbatim)
__global__ __launch_bounds__(512, 4) void k_attn(const float* __restrict__ x,
                                                 const unsigned short* __restrict__ m1A,
                                                 const float* __restrict__ cb1,
                                                 const unsigned short* __restrict__ vmb,
                                                 const float* __restrict__ gamma,
                                                 float* __restrict__ out) {
  __shared__ float e1w[8][32][17];
  __shared__ __align__(16) char p_t[4096];

  const int t = threadIdx.x;
  const int lane = t & 63;
  const int wv = t >> 6;
  const int b  = blockIdx.x >> 7;
  const int n0 = (blockIdx.x & 127) * 32;
  const int nrel = lane & 15;
  const int kg = lane >> 4;

  {
    f32x4 pacc[2] = {{0,0,0,0},{0,0,0,0}};
#pragma unroll
    for (int ktw = 0; ktw < 2; ++ktw) {
      int ktg = wv * 2 + ktw;
      shortx8 af = *(const shortx8*)(m1A + (size_t)b * 8192 +
                                     ((size_t)((ktg * 16 + nrel) * 4 + kg)) * 8);
#pragma unroll
      for (int nt = 0; nt < 2; ++nt) {
        const float* xp = x + (size_t)(b * 512 + wv * 64 + ktw * 32 + kg * 4) * NDIM +
                          n0 + nt * 16 + nrel;
        float v0 = xp[0],         v1 = xp[NDIM],       v2 = xp[2 * NDIM],  v3 = xp[3 * NDIM];
        float v4 = xp[16 * NDIM], v5 = xp[17 * NDIM],  v6 = xp[18 * NDIM], v7 = xp[19 * NDIM];
        shortx8 bf;
        unsigned* bu = (unsigned*)&bf;
        bu[0] = pk2(v0, v1); bu[1] = pk2(v2, v3);
        bu[2] = pk2(v4, v5); bu[3] = pk2(v6, v7);
        pacc[nt] = __builtin_amdgcn_mfma_f32_16x16x32_bf16(af, bf, pacc[nt], 0, 0, 0);
      }
    }
#pragma unroll
    for (int nt = 0; nt < 2; ++nt)
#pragma unroll
      for (int r = 0; r < 4; ++r)
        e1w[wv][nt * 16 + nrel][kg * 4 + r] = pacc[nt][r];
  }
  __syncthreads();

  {
    const int sn = t >> 4;
    const int si = t & 15;
    float ev = cb1[b * 16 + si];
#pragma unroll
    for (int g = 0; g < 8; ++g) ev += e1w[g][sn][si];
    float pv[4];
    float mx = -3.4e38f;
#pragma unroll
    for (int j = 0; j < 4; ++j) {
      int w = si * 4 + j;
      float srcf = (float)w * (15.0f / 63.0f);
      int i0 = (int)srcf;
      float tf = srcf - (float)i0;
      int i1 = i0 + 1; if (i1 > 15) i1 = 15;
      float v0 = __shfl(ev, (lane & 48) | i0);
      float v1 = __shfl(ev, (lane & 48) | i1);
      float vv = v0 * (1.0f - tf) + v1 * tf;
      pv[j] = vv;
      mx = fmaxf(mx, vv);
    }
    mx = fmaxf(mx, __shfl_xor(mx, 1));
    mx = fmaxf(mx, __shfl_xor(mx, 2));
    mx = fmaxf(mx, __shfl_xor(mx, 4));
    mx = fmaxf(mx, __shfl_xor(mx, 8));
    float s = 0.f;
#pragma unroll
    for (int j = 0; j < 4; ++j) { pv[j] = __expf(pv[j] - mx); s += pv[j]; }
    s += __shfl_xor(s, 1); s += __shfl_xor(s, 2);
    s += __shfl_xor(s, 4); s += __shfl_xor(s, 8);
    float inv = 1.0f / s;
    unsigned lo = pk2(pv[0] * inv, pv[1] * inv);
    unsigned hi = pk2(pv[2] * inv, pv[3] * inv);
    unsigned* dst = (unsigned*)(p_t + sn * 128 + ((si ^ (sn & 15)) << 3));
    dst[0] = lo; dst[1] = hi;
  }
  __syncthreads();

  {
    const float gm = gamma[0];
#pragma unroll
    for (int j = 0; j < 8; ++j) {
      const int idx = wv * 8 + j;
      const int ct = idx >> 1, nt = idx & 1;
      f32x4 dacc = {0.f, 0.f, 0.f, 0.f};
      const unsigned short* vrow =
          vmb + ((size_t)(b * CDIM + ct * 16 + nrel)) * 64 + kg * 4;
      const char* prow = p_t + (nt * 16 + nrel) * 128;
#pragma unroll
      for (int ks = 0; ks < 2; ++ks) {
        shortx4 a0 = *(const shortx4*)(vrow + ks * 32);
        shortx4 a1 = *(const shortx4*)(vrow + ks * 32 + 16);
        shortx8 av = __builtin_shufflevector(a0, a1, 0, 1, 2, 3, 4, 5, 6, 7);
        int G0 = (ks * 8 + kg) ^ nrel;
        int G1 = (ks * 8 + 4 + kg) ^ nrel;
        shortx4 b0 = *(const shortx4*)(prow + G0 * 8);
        shortx4 b1 = *(const shortx4*)(prow + G1 * 8);
        shortx8 bv2 = __builtin_shufflevector(b0, b1, 0, 1, 2, 3, 4, 5, 6, 7);
        dacc = __builtin_amdgcn_mfma_f32_16x16x32_bf16(av, bv2, dacc, 0, 0, 0);
      }
#pragma unroll
      for (int r = 0; r < 4; ++r) {
        int c_o = ct * 16 + kg * 4 + r;
        size_t base = (size_t)(b * CDIM + c_o) * NDIM + n0 + nt * 16 + nrel;
        out[base] = gm * dacc[r] + x[base];
      }
    }
  }
}

// ---------------------------------------------------------------------------
extern "C" void kernel_launch(void* const* d_in, const int* in_sizes, int n_in,
                              void* d_out, int out_size, void* d_ws, size_t ws_size,
                              hipStream_t stream) {
  const float* x     = (const float*)d_in[0];
  const float* Wq    = (const float*)d_in[1];
  const float* bq    = (const float*)d_in[2];
  const float* Wk    = (const float*)d_in[3];
  const float* bk    = (const float*)d_in[4];
  const float* Wv    = (const float*)d_in[5];
  const float* bv    = (const float*)d_in[6];
  const float* gamma = (const float*)d_in[7];
  const float* pe    = (const float*)d_in[8];
  const int*   pos   = (const int*)d_in[9];
  float* out = (float*)d_out;
  float* ws  = (float*)d_ws;

  float* xmh  = ws + OFF_XMH;
  float* x1pe = ws + OFF_X1;
  unsigned short* m1A = (unsigned short*)(ws + OFF_M1A);
  float* cb1  = ws + OFF_CB1;
  unsigned short* vmb = (unsigned short*)(ws + OFF_VMB);

  hipLaunchKernelGGL(k_reduce, dim3(512), dim3(256), 0, stream, x, pe, pos, xmh, x1pe);
  hipLaunchKernelGGL(k_mid, dim3(36), dim3(256), 0, stream,
                     Wv, bv, Wk, bk, Wq, bq, xmh, x1pe, vmb, m1A, cb1);
  hipLaunchKernelGGL(k_attn, dim3(512), dim3(512), 0, stream,
                     x, m1A, cb1, vmb, gamma, out);
}

// Round 9
// 135.427 us; speedup vs baseline: 1.4400x; 1.4400x over previous
//
#include <hip/hip_runtime.h>

#define CDIM 512
#define OKD  256
#define NDIM 4096

// ws float offsets
#define OFF_XMH 0          // fp32 B*C*64 = 131072
#define OFF_X1  131072     // fp32 B*C*16 = 32768
#define OFF_K1  163840     // fp32 B*256*16 = 16384
#define OFF_M1A 180224     // bf16 fragment-layout M1: 4b*8192 ushort = 16384 float slots
#define OFF_CB1 196608     // 64
#define OFF_VMB 196672     // bf16 vm [b][c][w]: 131072 ushort = 65536 float slots

typedef float f32x4  __attribute__((ext_vector_type(4)));
typedef short shortx4 __attribute__((ext_vector_type(4)));
typedef short shortx8 __attribute__((ext_vector_type(8)));

static __device__ __forceinline__ unsigned short f2bf(float f) {
  unsigned u = __float_as_uint(f);
  u = (u + 0x7FFFu + ((u >> 16) & 1u)) >> 16;
  return (unsigned short)u;
}
static __device__ __forceinline__ unsigned pk2(float lo, float hi) {
  return (unsigned)f2bf(lo) | ((unsigned)f2bf(hi) << 16);
}

// ---------------------------------------------------------------------------
// K1: x -> xmh[b,c,64] (h-mean, fp32) and x1pe[b,c,16] (h-mean + 4w-mean + pe)
__global__ __launch_bounds__(256) void k_reduce(const float* __restrict__ x,
                                                const float* __restrict__ pe,
                                                const int* __restrict__ pos,
                                                float* __restrict__ xmh,
                                                float* __restrict__ x1pe) {
  int t = threadIdx.x;
  int bc = blockIdx.x * 4 + (t >> 6);   // B*C = 2048, grid 512
  int w4 = t & 15;
  int hoff = (t >> 4) & 3;
  const float4* xp = (const float4*)(x) + (size_t)bc * (64 * 16);
  float4 acc = make_float4(0.f, 0.f, 0.f, 0.f);
#pragma unroll
  for (int k = 0; k < 16; ++k) {
    float4 v = xp[(hoff + 4 * k) * 16 + w4];
    acc.x += v.x; acc.y += v.y; acc.z += v.z; acc.w += v.w;
  }
  acc.x += __shfl_xor(acc.x, 16); acc.y += __shfl_xor(acc.y, 16);
  acc.z += __shfl_xor(acc.z, 16); acc.w += __shfl_xor(acc.w, 16);
  acc.x += __shfl_xor(acc.x, 32); acc.y += __shfl_xor(acc.y, 32);
  acc.z += __shfl_xor(acc.z, 32); acc.w += __shfl_xor(acc.w, 32);
  if (hoff == 0) {
    const float inv = 1.f / 64.f;
    float4 o = make_float4(acc.x * inv, acc.y * inv, acc.z * inv, acc.w * inv);
    ((float4*)xmh)[bc * 16 + w4] = o;
    int b = bc >> 9;
    int c = bc & 511;
    int ps = pos[b * 4096 + 4 * w4] >> 3;
    float x1 = (o.x + o.y + o.z + o.w) * 0.25f + pe[ps * CDIM + c];
    x1pe[bc * 16 + w4] = x1;
  }
}

// ---------------------------------------------------------------------------
// K2 (128 thr):
//  blocks 0..63:  vm MFMA: vmb[b,c,w] = bf16(Wv@xmh + bv)
//  blocks 64..191: K1[b,o,i] = Wk@x1pe + bk (VALU)
__global__ __launch_bounds__(128) void k_vmk1(const float* __restrict__ Wv,
                                              const float* __restrict__ bv,
                                              const float* __restrict__ Wk,
                                              const float* __restrict__ bk,
                                              const float* __restrict__ xmh,
                                              const float* __restrict__ x1pe,
                                              unsigned short* __restrict__ vmb,
                                              float* __restrict__ K1) {
  int t = threadIdx.x;
  int blk = blockIdx.x;
  if (blk < 64) {
    int wid = blk * 2 + (t >> 6);
    int lane = t & 63, nrel = lane & 15, kg = lane >> 4;
    int b = wid >> 5, rem = wid & 31, cgrp = rem >> 2, wt = rem & 3;
    f32x4 acc[4] = {{0,0,0,0},{0,0,0,0},{0,0,0,0},{0,0,0,0}};
    for (int kt = 0; kt < 16; ++kt) {
      const float* xp = xmh + (size_t)(b * 512 + kt * 32 + kg * 4) * 64 + wt * 16 + nrel;
      float v0 = xp[0], v1 = xp[64], v2 = xp[128], v3 = xp[192];
      float v4 = xp[1024], v5 = xp[1088], v6 = xp[1152], v7 = xp[1216];
      shortx8 bf;
      unsigned* bu = (unsigned*)&bf;
      bu[0] = pk2(v0, v1); bu[1] = pk2(v2, v3);
      bu[2] = pk2(v4, v5); bu[3] = pk2(v6, v7);
#pragma unroll
      for (int m = 0; m < 4; ++m) {
        int c = (cgrp * 4 + m) * 16 + nrel;
        const float* wp = Wv + (size_t)c * 512 + kt * 32 + kg * 4;
        float4 a0 = *(const float4*)wp;
        float4 a1 = *(const float4*)(wp + 16);
        shortx8 af;
        unsigned* au = (unsigned*)&af;
        au[0] = pk2(a0.x, a0.y); au[1] = pk2(a0.z, a0.w);
        au[2] = pk2(a1.x, a1.y); au[3] = pk2(a1.z, a1.w);
        acc[m] = __builtin_amdgcn_mfma_f32_16x16x32_bf16(af, bf, acc[m], 0, 0, 0);
      }
    }
#pragma unroll
    for (int m = 0; m < 4; ++m)
#pragma unroll
      for (int r = 0; r < 4; ++r) {
        int c = (cgrp * 4 + m) * 16 + kg * 4 + r;
        vmb[(size_t)(b * 512 + c) * 64 + wt * 16 + nrel] = f2bf(acc[m][r] + bv[c]);
      }
  } else {
    int idx = blk - 64;                 // 0..127
    int b = idx >> 5, og = idx & 31;
    int o = og * 8 + (t >> 4), i = t & 15;
    const float* Wr = Wk + (size_t)o * 512;
    const float* xb = x1pe + ((size_t)b * 512) * 16 + i;
    float a0 = 0.f, a1 = 0.f, a2 = 0.f, a3 = 0.f;
    for (int c = 0; c < 512; c += 4) {
      a0 += Wr[c]     * xb[c * 16];
      a1 += Wr[c + 1] * xb[(c + 1) * 16];
      a2 += Wr[c + 2] * xb[(c + 2) * 16];
      a3 += Wr[c + 3] * xb[(c + 3) * 16];
    }
    K1[((b << 8) + o) * 16 + i] = bk[o] + a0 + a1 + a2 + a3;
  }
}

// ---------------------------------------------------------------------------
// K3: m1A = bf16-fragment(Wq^T @ K1) via MFMA (blocks 0..31);
//     cb1[b,i] = bq . K1 (block 32)
__global__ __launch_bounds__(256) void k_m1(const float* __restrict__ Wq,
                                            const float* __restrict__ bq,
                                            const float* __restrict__ K1,
                                            unsigned short* __restrict__ m1A,
                                            float* __restrict__ cb1) {
  int t = threadIdx.x;
  int blk = blockIdx.x;
  if (blk < 32) {
    int lane = t & 63, nrel = lane & 15, kg = lane >> 4;
    int job = blk * 4 + (t >> 6);        // 0..127
    int b = job >> 5, ct = job & 31;
    f32x4 acc = {0.f, 0.f, 0.f, 0.f};
#pragma unroll
    for (int kt = 0; kt < 8; ++kt) {
      const float* wqp = Wq + (size_t)(kt * 32 + kg * 4) * CDIM + ct * 16 + nrel;
      float a0 = wqp[0],          a1 = wqp[CDIM],      a2 = wqp[2 * CDIM],  a3 = wqp[3 * CDIM];
      float a4 = wqp[16 * CDIM],  a5 = wqp[17 * CDIM], a6 = wqp[18 * CDIM], a7 = wqp[19 * CDIM];
      shortx8 af;
      unsigned* au = (unsigned*)&af;
      au[0] = pk2(a0, a1); au[1] = pk2(a2, a3);
      au[2] = pk2(a4, a5); au[3] = pk2(a6, a7);
      const float* kp = K1 + ((size_t)(b * 256 + kt * 32 + kg * 4)) * 16 + nrel;
      float b0 = kp[0],   b1 = kp[16],  b2 = kp[32],  b3 = kp[48];
      float b4 = kp[256], b5 = kp[272], b6 = kp[288], b7 = kp[304];
      shortx8 bf;
      unsigned* bu = (unsigned*)&bf;
      bu[0] = pk2(b0, b1); bu[1] = pk2(b2, b3);
      bu[2] = pk2(b4, b5); bu[3] = pk2(b6, b7);
      acc = __builtin_amdgcn_mfma_f32_16x16x32_bf16(af, bf, acc, 0, 0, 0);
    }
#pragma unroll
    for (int r = 0; r < 4; ++r) {
      int c = ct * 16 + kg * 4 + r;       // D row; col = i = nrel
      int ktm = c >> 5, klm = c & 31;
      int kgm = (klm < 16) ? (klm >> 2) : ((klm - 16) >> 2);
      int jm = (klm & 3) + ((klm < 16) ? 0 : 4);
      m1A[(size_t)b * 8192 + ((size_t)(ktm * 16 + nrel) * 4 + kgm) * 8 + jm] = f2bf(acc[r]);
    }
  } else if (t < 64) {
    int b = t >> 4, i = t & 15;
    const float* Kb = K1 + (b << 8) * 16 + i;
    float acc = 0.f;
    for (int o = 0; o < OKD; ++o) acc += bq[o] * Kb[o * 16];
    cb1[b * 16 + i] = acc;
  }
}

// ---------------------------------------------------------------------------
// K4: fused attention per (b, 32-n tile), 512 thr, 2 barriers.
//  Phase A/B: R5 verbatim. Phase C: MFMA PV, then per-wave LDS transpose of
//  the 16x16 D tile (e1w reused as wave-private scratch, 20-padded rows) so
//  the residual+store epilogue is float4 along n (1 load + 1 store per lane).
__global__ __launch_bounds__(512, 4) void k_attn(const float* __restrict__ x,
                                                 const unsigned short* __restrict__ m1A,
                                                 const float* __restrict__ cb1,
                                                 const unsigned short* __restrict__ vmb,
                                                 const float* __restrict__ gamma,
                                                 float* __restrict__ out) {
  __shared__ float e1w[8][32][17];          // phase A partials; phase C scratch
  __shared__ __align__(16) char p_t[4096];

  const int t = threadIdx.x;
  const int lane = t & 63;
  const int wv = t >> 6;
  const int b  = blockIdx.x >> 7;
  const int n0 = (blockIdx.x & 127) * 32;
  const int nrel = lane & 15;
  const int kg = lane >> 4;

  {
    f32x4 pacc[2] = {{0,0,0,0},{0,0,0,0}};
#pragma unroll
    for (int ktw = 0; ktw < 2; ++ktw) {
      int ktg = wv * 2 + ktw;
      shortx8 af = *(const shortx8*)(m1A + (size_t)b * 8192 +
                                     ((size_t)((ktg * 16 + nrel) * 4 + kg)) * 8);
#pragma unroll
      for (int nt = 0; nt < 2; ++nt) {
        const float* xp = x + (size_t)(b * 512 + wv * 64 + ktw * 32 + kg * 4) * NDIM +
                          n0 + nt * 16 + nrel;
        float v0 = xp[0],         v1 = xp[NDIM],       v2 = xp[2 * NDIM],  v3 = xp[3 * NDIM];
        float v4 = xp[16 * NDIM], v5 = xp[17 * NDIM],  v6 = xp[18 * NDIM], v7 = xp[19 * NDIM];
        shortx8 bf;
        unsigned* bu = (unsigned*)&bf;
        bu[0] = pk2(v0, v1); bu[1] = pk2(v2, v3);
        bu[2] = pk2(v4, v5); bu[3] = pk2(v6, v7);
        pacc[nt] = __builtin_amdgcn_mfma_f32_16x16x32_bf16(af, bf, pacc[nt], 0, 0, 0);
      }
    }
#pragma unroll
    for (int nt = 0; nt < 2; ++nt)
#pragma unroll
      for (int r = 0; r < 4; ++r)
        e1w[wv][nt * 16 + nrel][kg * 4 + r] = pacc[nt][r];
  }
  __syncthreads();

  {
    const int sn = t >> 4;
    const int si = t & 15;
    float ev = cb1[b * 16 + si];
#pragma unroll
    for (int g = 0; g < 8; ++g) ev += e1w[g][sn][si];
    float pv[4];
    float mx = -3.4e38f;
#pragma unroll
    for (int j = 0; j < 4; ++j) {
      int w = si * 4 + j;
      float srcf = (float)w * (15.0f / 63.0f);
      int i0 = (int)srcf;
      float tf = srcf - (float)i0;
      int i1 = i0 + 1; if (i1 > 15) i1 = 15;
      float v0 = __shfl(ev, (lane & 48) | i0);
      float v1 = __shfl(ev, (lane & 48) | i1);
      float vv = v0 * (1.0f - tf) + v1 * tf;
      pv[j] = vv;
      mx = fmaxf(mx, vv);
    }
    mx = fmaxf(mx, __shfl_xor(mx, 1));
    mx = fmaxf(mx, __shfl_xor(mx, 2));
    mx = fmaxf(mx, __shfl_xor(mx, 4));
    mx = fmaxf(mx, __shfl_xor(mx, 8));
    float s = 0.f;
#pragma unroll
    for (int j = 0; j < 4; ++j) { pv[j] = __expf(pv[j] - mx); s += pv[j]; }
    s += __shfl_xor(s, 1); s += __shfl_xor(s, 2);
    s += __shfl_xor(s, 4); s += __shfl_xor(s, 8);
    float inv = 1.0f / s;
    unsigned lo = pk2(pv[0] * inv, pv[1] * inv);
    unsigned hi = pk2(pv[2] * inv, pv[3] * inv);
    unsigned* dst = (unsigned*)(p_t + sn * 128 + ((si ^ (sn & 15)) << 3));
    dst[0] = lo; dst[1] = hi;
  }
  __syncthreads();   // protects p_t AND marks e1w dead -> reusable as scratch

  {
    const float gm = gamma[0];
    float* scr = &e1w[0][0][0] + wv * 544;   // wave-private, 320 of 544 used
    const int cl = lane >> 2;                // 0..15
    const int nq = lane & 3;                 // 0..3
#pragma unroll
    for (int j = 0; j < 8; ++j) {
      const int idx = wv * 8 + j;
      const int ct = idx >> 1, nt = idx & 1;
      f32x4 dacc = {0.f, 0.f, 0.f, 0.f};
      const unsigned short* vrow =
          vmb + ((size_t)(b * CDIM + ct * 16 + nrel)) * 64 + kg * 4;
      const char* prow = p_t + (nt * 16 + nrel) * 128;
#pragma unroll
      for (int ks = 0; ks < 2; ++ks) {
        shortx4 a0 = *(const shortx4*)(vrow + ks * 32);
        shortx4 a1 = *(const shortx4*)(vrow + ks * 32 + 16);
        shortx8 av = __builtin_shufflevector(a0, a1, 0, 1, 2, 3, 4, 5, 6, 7);
        int G0 = (ks * 8 + kg) ^ nrel;
        int G1 = (ks * 8 + 4 + kg) ^ nrel;
        shortx4 b0 = *(const shortx4*)(prow + G0 * 8);
        shortx4 b1 = *(const shortx4*)(prow + G1 * 8);
        shortx8 bv2 = __builtin_shufflevector(b0, b1, 0, 1, 2, 3, 4, 5, 6, 7);
        dacc = __builtin_amdgcn_mfma_f32_16x16x32_bf16(av, bv2, dacc, 0, 0, 0);
      }
      // transpose 16x16 D tile in wave-private LDS: [c][n], rows padded to 20
#pragma unroll
      for (int r = 0; r < 4; ++r)
        scr[(kg * 4 + r) * 20 + nrel] = gm * dacc[r];
      f32x4 dv = *(f32x4*)&scr[cl * 20 + nq * 4];
      size_t base = (size_t)(b * CDIM + ct * 16 + cl) * NDIM + n0 + nt * 16 + nq * 4;
      float4 xr = *(const float4*)&x[base];
      float4 o;
      o.x = dv[0] + xr.x;
      o.y = dv[1] + xr.y;
      o.z = dv[2] + xr.z;
      o.w = dv[3] + xr.w;
      *(float4*)&out[base] = o;
    }
  }
}

// ---------------------------------------------------------------------------
extern "C" void kernel_launch(void* const* d_in, const int* in_sizes, int n_in,
                              void* d_out, int out_size, void* d_ws, size_t ws_size,
                              hipStream_t stream) {
  const float* x     = (const float*)d_in[0];
  const float* Wq    = (const float*)d_in[1];
  const float* bq    = (const float*)d_in[2];
  const float* Wk    = (const float*)d_in[3];
  const float* bk    = (const float*)d_in[4];
  const float* Wv    = (const float*)d_in[5];
  const float* bv    = (const float*)d_in[6];
  const float* gamma = (const float*)d_in[7];
  const float* pe    = (const float*)d_in[8];
  const int*   pos   = (const int*)d_in[9];
  float* out = (float*)d_out;
  float* ws  = (float*)d_ws;

  float* xmh  = ws + OFF_XMH;
  float* x1pe = ws + OFF_X1;
  float* K1   = ws + OFF_K1;
  unsigned short* m1A = (unsigned short*)(ws + OFF_M1A);
  float* cb1  = ws + OFF_CB1;
  unsigned short* vmb = (unsigned short*)(ws + OFF_VMB);

  hipLaunchKernelGGL(k_reduce, dim3(512), dim3(256), 0, stream, x, pe, pos, xmh, x1pe);
  hipLaunchKernelGGL(k_vmk1, dim3(192), dim3(128), 0, stream, Wv, bv, Wk, bk, xmh, x1pe, vmb, K1);
  hipLaunchKernelGGL(k_m1, dim3(33), dim3(256), 0, stream, Wq, bq, K1, m1A, cb1);
  hipLaunchKernelGGL(k_attn, dim3(512), dim3(512), 0, stream, x, m1A, cb1, vmb, gamma, out);
}